// Round 13
// baseline (339.105 us; speedup 1.0000x reference)
//
#include <hip/hip_runtime.h>

#define NTOK 8192
#define CDIM 1024
#define HDIM 128

typedef __attribute__((ext_vector_type(8))) short short8;
typedef __attribute__((ext_vector_type(4))) float floatx4;
typedef __attribute__((ext_vector_type(16))) float floatx16;

__device__ inline unsigned short f2bf(float f) {
    union { float f; unsigned u; } v; v.f = f;
    unsigned r = v.u + 0x7fffu + ((v.u >> 16) & 1u);
    return (unsigned short)(r >> 16);
}
__device__ inline float bf2f(short s) {
    union { unsigned u; float f; } v;
    v.u = ((unsigned)(unsigned short)s) << 16;
    return v.f;
}
__device__ inline void async16(const unsigned short* g, short* l) {
    __builtin_amdgcn_global_load_lds(
        (const __attribute__((address_space(1))) unsigned*)g,
        (__attribute__((address_space(3))) unsigned*)l, 16, 0, 0);
}

// ---------------- fused cast fp32 -> bf16 for all 5 inputs (one launch) ----------------
__global__ __launch_bounds__(256) void cast_all(
    const float* __restrict__ x,  const float* __restrict__ Wv,
    const float* __restrict__ Wo, const float* __restrict__ Wq,
    const float* __restrict__ Wk,
    unsigned short* __restrict__ xo, unsigned short* __restrict__ wvo,
    unsigned short* __restrict__ woo, unsigned short* __restrict__ wqo,
    unsigned short* __restrict__ wko)
{
    int b = blockIdx.x;
    const float* in; unsigned short* out; int base;
    if (b < 8192)       { in = x;  out = xo;  base = b; }
    else if (b < 9216)  { in = Wv; out = wvo; base = b - 8192; }
    else if (b < 10240) { in = Wo; out = woo; base = b - 9216; }
    else if (b < 10368) { in = Wq; out = wqo; base = b - 10240; }
    else                { in = Wk; out = wko; base = b - 10368; }
    int i = base * 256 + threadIdx.x;
    float4 v = ((const float4*)in)[i];
    ushort4 o;
    o.x = f2bf(v.x); o.y = f2bf(v.y); o.z = f2bf(v.z); o.w = f2bf(v.w);
    ((ushort4*)out)[i] = o;
}

// ---------------- unified q/k/v projection: 128-tile NT GEMM, T3/T4 K-loop ----------------
// grid (64, 10): y=0 -> q (row-major bf16), y=1 -> k (K-swz), y>=2 -> v (V-swz, n0=(y-2)*128)
// 3 blocks/CU: 640-block grid runs in one fill.
__global__ __launch_bounds__(256, 3) void gemm_proj(
    const unsigned short* __restrict__ A,
    const unsigned short* __restrict__ Wq, const float* __restrict__ bq,
    const unsigned short* __restrict__ Wk, const float* __restrict__ bk,
    const unsigned short* __restrict__ Wv, const float* __restrict__ bv,
    unsigned short* __restrict__ qout, unsigned short* __restrict__ kout,
    unsigned short* __restrict__ vout)
{
    __shared__ short As[3][128][4][8]; // 3 x 8 KB
    __shared__ short Ws[3][128][4][8];
    const int tid = threadIdx.x, wave = tid >> 6, lane = tid & 63;
    const int lr = lane & 15, lc = lane >> 4;
    const int wm = (wave >> 1) * 64, wn = (wave & 1) * 64;
    const int m0 = blockIdx.x * 128;
    const int y = blockIdx.y;

    const unsigned short* W; const float* bias; int n0;
    if (y == 0)      { W = Wq; bias = bq; n0 = 0; }
    else if (y == 1) { W = Wk; bias = bk; n0 = 0; }
    else             { W = Wv; bias = bv; n0 = (y - 2) * 128; }

    floatx4 acc[4][4] = {};

    const int srow = lane >> 2, sch = lane & 3;
    const unsigned short* Ag0 = A + (long)(m0 + wave * 32 + srow) * CDIM + sch * 8;
    const unsigned short* Ag1 = Ag0 + (long)16 * CDIM;
    const unsigned short* Wg0 = W + (long)(n0 + wave * 32 + srow) * CDIM + sch * 8;
    const unsigned short* Wg1 = Wg0 + (long)16 * CDIM;

    short* ar = &As[0][0][0][0]; short* aw = &As[1][0][0][0]; short* a2 = &As[2][0][0][0];
    short* wr = &Ws[0][0][0][0]; short* ww = &Ws[1][0][0][0]; short* w2 = &Ws[2][0][0][0];

#define GSTAGE(K0, AD, WD) {                          \
        async16(Ag0 + (K0), (AD) + wave * 1024);      \
        async16(Ag1 + (K0), (AD) + wave * 1024 + 512);\
        async16(Wg0 + (K0), (WD) + wave * 1024);      \
        async16(Wg1 + (K0), (WD) + wave * 1024 + 512); }

    GSTAGE(0, ar, wr);
    for (int k0 = 0; k0 < CDIM; k0 += 32) {
        if (k0 + 32 < CDIM) {
            GSTAGE(k0 + 32, aw, ww);
            __builtin_amdgcn_sched_barrier(0);
            asm volatile("s_waitcnt vmcnt(4)" ::: "memory");
        } else {
            asm volatile("s_waitcnt vmcnt(0)" ::: "memory");
        }
        __builtin_amdgcn_sched_barrier(0);
        __builtin_amdgcn_s_barrier();
        __builtin_amdgcn_sched_barrier(0);
        short8 af[4], bfg[4];
#pragma unroll
        for (int i = 0; i < 4; i++) af[i]  = *(short8*)(ar + (wm + i * 16 + lr) * 32 + lc * 8);
#pragma unroll
        for (int j = 0; j < 4; j++) bfg[j] = *(short8*)(wr + (wn + j * 16 + lr) * 32 + lc * 8);
#pragma unroll
        for (int i = 0; i < 4; i++)
#pragma unroll
            for (int j = 0; j < 4; j++)
                acc[i][j] = __builtin_amdgcn_mfma_f32_16x16x32_bf16(af[i], bfg[j], acc[i][j], 0, 0, 0);
        short* t;
        t = ar; ar = aw; aw = a2; a2 = t;
        t = wr; wr = ww; ww = w2; w2 = t;
    }
#undef GSTAGE

#pragma unroll
    for (int i = 0; i < 4; i++) {
        int t0 = m0 + wm + i * 16 + lc * 4;
#pragma unroll
        for (int j = 0; j < 4; j++) {
            int c = n0 + wn + j * 16 + lr;  // absolute for v; ==local for q/k (n0=0)
            float bb = bias[c];
            if (y == 0) {
#pragma unroll
                for (int r = 0; r < 4; r++)
                    qout[(long)(t0 + r) * HDIM + c] = f2bf(acc[i][j][r] + bb);
            } else if (y == 1) {
#pragma unroll
                for (int r = 0; r < 4; r++) {
                    int tok = t0 + r;
                    kout[(tok >> 5) * 4096 + (c >> 3) * 256 + (tok & 31) * 8 + (c & 7)] =
                        f2bf(acc[i][j][r] + bb);
                }
            } else {
                ushort4 pk;
                pk.x = f2bf(acc[i][j][0] + bb); pk.y = f2bf(acc[i][j][1] + bb);
                pk.z = f2bf(acc[i][j][2] + bb); pk.w = f2bf(acc[i][j][3] + bb);
                long off = (long)(c >> 8) * 2097152 + (t0 >> 5) * 8192 +
                           ((t0 & 31) >> 3) * 2048 + (c & 255) * 8 + (t0 & 7);
                *(ushort4*)&vout[off] = pk;
            }
        }
    }
}

// ---------------- output projection: 128-tile NT GEMM, T3/T4 K-loop, f32 out ----------------
__global__ __launch_bounds__(256, 3) void gemm_out(
    const unsigned short* __restrict__ A, const unsigned short* __restrict__ W,
    const float* __restrict__ bias, float* __restrict__ out)
{
    __shared__ short As[3][128][4][8];
    __shared__ short Ws[3][128][4][8];
    const int tid = threadIdx.x, wave = tid >> 6, lane = tid & 63;
    const int lr = lane & 15, lc = lane >> 4;
    const int wm = (wave >> 1) * 64, wn = (wave & 1) * 64;
    const int m0 = blockIdx.x * 128, n0 = blockIdx.y * 128;

    floatx4 acc[4][4] = {};

    const int srow = lane >> 2, sch = lane & 3;
    const unsigned short* Ag0 = A + (long)(m0 + wave * 32 + srow) * CDIM + sch * 8;
    const unsigned short* Ag1 = Ag0 + (long)16 * CDIM;
    const unsigned short* Wg0 = W + (long)(n0 + wave * 32 + srow) * CDIM + sch * 8;
    const unsigned short* Wg1 = Wg0 + (long)16 * CDIM;

    short* ar = &As[0][0][0][0]; short* aw = &As[1][0][0][0]; short* a2 = &As[2][0][0][0];
    short* wr = &Ws[0][0][0][0]; short* ww = &Ws[1][0][0][0]; short* w2 = &Ws[2][0][0][0];

#define GSTAGE(K0, AD, WD) {                          \
        async16(Ag0 + (K0), (AD) + wave * 1024);      \
        async16(Ag1 + (K0), (AD) + wave * 1024 + 512);\
        async16(Wg0 + (K0), (WD) + wave * 1024);      \
        async16(Wg1 + (K0), (WD) + wave * 1024 + 512); }

    GSTAGE(0, ar, wr);
    for (int k0 = 0; k0 < CDIM; k0 += 32) {
        if (k0 + 32 < CDIM) {
            GSTAGE(k0 + 32, aw, ww);
            __builtin_amdgcn_sched_barrier(0);
            asm volatile("s_waitcnt vmcnt(4)" ::: "memory");
        } else {
            asm volatile("s_waitcnt vmcnt(0)" ::: "memory");
        }
        __builtin_amdgcn_sched_barrier(0);
        __builtin_amdgcn_s_barrier();
        __builtin_amdgcn_sched_barrier(0);
        short8 af[4], bfg[4];
#pragma unroll
        for (int i = 0; i < 4; i++) af[i]  = *(short8*)(ar + (wm + i * 16 + lr) * 32 + lc * 8);
#pragma unroll
        for (int j = 0; j < 4; j++) bfg[j] = *(short8*)(wr + (wn + j * 16 + lr) * 32 + lc * 8);
#pragma unroll
        for (int i = 0; i < 4; i++)
#pragma unroll
            for (int j = 0; j < 4; j++)
                acc[i][j] = __builtin_amdgcn_mfma_f32_16x16x32_bf16(af[i], bfg[j], acc[i][j], 0, 0, 0);
        short* t;
        t = ar; ar = aw; aw = a2; a2 = t;
        t = wr; wr = ww; ww = w2; w2 = t;
    }
#undef GSTAGE

#pragma unroll
    for (int i = 0; i < 4; i++) {
        int t0 = m0 + wm + i * 16 + lc * 4;
#pragma unroll
        for (int j = 0; j < 4; j++) {
            int c = n0 + wn + j * 16 + lr;
            float bb = bias[c];
#pragma unroll
            for (int r = 0; r < 4; r++) out[(long)(t0 + r) * CDIM + c] = acc[i][j][r] + bb;
        }
    }
}

// ---------------- fused attention: partial O = exp(QK^T*scale) @ V + rowsum ----------------
// ROUND 13: T15-style deferred PV (single-tile variant). Phase p: PV_t1(p-1) runs FIRST
// (pa-frags in regs, V-slot (p-1)%3 still live -- with the 3-slot rotation all three slots
// are valid simultaneously: read-PV(p-1), read-QK(p), write(p+1), pairwise distinct mod 3).
// Then QK(p) both tiles, exp(t0)->PV(t0), exp(t1) packs into the deferred regs and hangs
// past the barrier (s_barrier doesn't wait on VALU results). Holds +2 short8 (8 VGPR):
// 244+8=252 <= 256 keeps 2 waves/SIMD. Epilogue peels PV_t1(63).
__global__ __launch_bounds__(512, 2) void attn_pv(
    const unsigned short* __restrict__ qb, const unsigned short* __restrict__ ksw,
    const unsigned short* __restrict__ vsw,
    unsigned short* __restrict__ Oa, unsigned short* __restrict__ Ob,
    float* __restrict__ la, float* __restrict__ lb)
{
    __shared__ short Ks[3][8192];   // 48 KB
    __shared__ short Vs[3][16384];  // 96 KB

    const int tid = threadIdx.x, wave = tid >> 6, lane = tid & 63;
    const int l31 = lane & 31, h = lane >> 5;
    const int m0 = blockIdx.x * 256, cblk = blockIdx.y;
    const int mw = m0 + wave * 32;
    const int nt0 = blockIdx.z * 128;
    unsigned short* Op = blockIdx.z ? Ob : Oa;
    float* ls = blockIdx.z ? lb : la;
    const float cexp = (float)(0.08838834764831845 * 1.4426950408889634);

    short8 qf[8];
#pragma unroll
    for (int kk = 0; kk < 8; kk++)
        qf[kk] = *(const short8*)&qb[(mw + l31) * HDIM + kk * 16 + h * 8];

    floatx16 acc[8] = {};
    float ls0 = 0.f, ls1 = 0.f, ls2 = 0.f, ls3 = 0.f;

    const unsigned short* kg0 = ksw + (wave * 2 + 0) * 512 + lane * 8;
    const unsigned short* kg1 = ksw + (wave * 2 + 1) * 512 + lane * 8;
    const unsigned short* vgb = vsw + (long)cblk * 2097152 + lane * 8;
    const unsigned short* vg0 = vgb + (wave * 4 + 0) * 512;
    const unsigned short* vg1 = vgb + (wave * 4 + 1) * 512;
    const unsigned short* vg2 = vgb + (wave * 4 + 2) * 512;
    const unsigned short* vg3 = vgb + (wave * 4 + 3) * 512;

    short* kr = &Ks[0][0];
    short* kw = &Ks[1][0];
    short* k2 = &Ks[2][0];
    short* vr = &Vs[0][0];
    short* vw = &Vs[1][0];
    short* v2 = &Vs[2][0];

    short8 pp0, pp1;            // deferred tile-1 P-frags (prev phase)
    short* vprev = &Vs[0][0];   // V phase-slot of prev phase (set each iter)

#define STAGE(P, KD, VD)                                                \
    {                                                                   \
        long ok_ = (long)(nt0 + 2 * (P)) * 4096;                        \
        long ov_ = (long)(nt0 + 2 * (P)) * 8192;                        \
        async16(kg0 + ok_, (KD) + (wave * 2 + 0) * 512);                \
        async16(kg1 + ok_, (KD) + (wave * 2 + 1) * 512);                \
        async16(vg0 + ov_, (VD) + (wave * 4 + 0) * 512);                \
        async16(vg1 + ov_, (VD) + (wave * 4 + 1) * 512);                \
        async16(vg2 + ov_, (VD) + (wave * 4 + 2) * 512);                \
        async16(vg3 + ov_, (VD) + (wave * 4 + 3) * 512);                \
    }

#define EXP_PACK(ST, PA0, PA1)                                                      \
        {                                                                           \
            unsigned pk0, pk1, pk2, pk3, pk4, pk5, pk6, pk7;                        \
            float p0, p1;                                                           \
            p0 = __builtin_amdgcn_exp2f(ST[0] * cexp);                              \
            p1 = __builtin_amdgcn_exp2f(ST[1] * cexp);                              \
            ls0 += p0 + p1;                                                         \
            asm("v_cvt_pk_bf16_f32 %0, %1, %2" : "=v"(pk0) : "v"(p0), "v"(p1));     \
            p0 = __builtin_amdgcn_exp2f(ST[2] * cexp);                              \
            p1 = __builtin_amdgcn_exp2f(ST[3] * cexp);                              \
            ls1 += p0 + p1;                                                         \
            asm("v_cvt_pk_bf16_f32 %0, %1, %2" : "=v"(pk1) : "v"(p0), "v"(p1));     \
            p0 = __builtin_amdgcn_exp2f(ST[4] * cexp);                              \
            p1 = __builtin_amdgcn_exp2f(ST[5] * cexp);                              \
            ls2 += p0 + p1;                                                         \
            asm("v_cvt_pk_bf16_f32 %0, %1, %2" : "=v"(pk2) : "v"(p0), "v"(p1));     \
            p0 = __builtin_amdgcn_exp2f(ST[6] * cexp);                              \
            p1 = __builtin_amdgcn_exp2f(ST[7] * cexp);                              \
            ls3 += p0 + p1;                                                         \
            asm("v_cvt_pk_bf16_f32 %0, %1, %2" : "=v"(pk3) : "v"(p0), "v"(p1));     \
            p0 = __builtin_amdgcn_exp2f(ST[8] * cexp);                              \
            p1 = __builtin_amdgcn_exp2f(ST[9] * cexp);                              \
            ls0 += p0 + p1;                                                         \
            asm("v_cvt_pk_bf16_f32 %0, %1, %2" : "=v"(pk4) : "v"(p0), "v"(p1));     \
            p0 = __builtin_amdgcn_exp2f(ST[10] * cexp);                             \
            p1 = __builtin_amdgcn_exp2f(ST[11] * cexp);                             \
            ls1 += p0 + p1;                                                         \
            asm("v_cvt_pk_bf16_f32 %0, %1, %2" : "=v"(pk5) : "v"(p0), "v"(p1));     \
            p0 = __builtin_amdgcn_exp2f(ST[12] * cexp);                             \
            p1 = __builtin_amdgcn_exp2f(ST[13] * cexp);                             \
            ls2 += p0 + p1;                                                         \
            asm("v_cvt_pk_bf16_f32 %0, %1, %2" : "=v"(pk6) : "v"(p0), "v"(p1));     \
            p0 = __builtin_amdgcn_exp2f(ST[14] * cexp);                             \
            p1 = __builtin_amdgcn_exp2f(ST[15] * cexp);                             \
            ls3 += p0 + p1;                                                         \
            asm("v_cvt_pk_bf16_f32 %0, %1, %2" : "=v"(pk7) : "v"(p0), "v"(p1));     \
            asm("v_permlane32_swap_b32 %0, %1" : "+v"(pk0), "+v"(pk2));             \
            asm("v_permlane32_swap_b32 %0, %1" : "+v"(pk1), "+v"(pk3));             \
            asm("v_permlane32_swap_b32 %0, %1" : "+v"(pk4), "+v"(pk6));             \
            asm("v_permlane32_swap_b32 %0, %1" : "+v"(pk5), "+v"(pk7));             \
            union { unsigned u[4]; short8 s; } up0_, up1_;                          \
            up0_.u[0] = pk0; up0_.u[1] = pk1; up0_.u[2] = pk2; up0_.u[3] = pk3;     \
            up1_.u[0] = pk4; up1_.u[1] = pk5; up1_.u[2] = pk6; up1_.u[3] = pk7;     \
            PA0 = up0_.s; PA1 = up1_.s;                                             \
        }

#define PV(VB, PA0, PA1)                                                            \
        __builtin_amdgcn_s_setprio(1);                                              \
        _Pragma("unroll")                                                           \
        for (int ct = 0; ct < 8; ct++) {                                            \
            short8 bv0 = *(short8*)((VB) + h * 2048 + (ct * 32 + l31) * 8);         \
            short8 bv1 = *(short8*)((VB) + (2 + h) * 2048 + (ct * 32 + l31) * 8);   \
            acc[ct] = __builtin_amdgcn_mfma_f32_32x32x16_bf16(PA0, bv0, acc[ct], 0, 0, 0); \
            acc[ct] = __builtin_amdgcn_mfma_f32_32x32x16_bf16(PA1, bv1, acc[ct], 0, 0, 0); \
        }                                                                           \
        __builtin_amdgcn_s_setprio(0);

    STAGE(0, kr, vr);

    for (int ph = 0; ph < 64; ++ph) {
        if (ph + 1 < 64) STAGE(ph + 1, kw, vw);
        __builtin_amdgcn_sched_barrier(0);
        if (ph == 63) asm volatile("s_waitcnt vmcnt(0)" ::: "memory");
        else          asm volatile("s_waitcnt vmcnt(6)" ::: "memory");
        __builtin_amdgcn_sched_barrier(0);
        __builtin_amdgcn_s_barrier();
        __builtin_amdgcn_sched_barrier(0);

        short* kb0 = kr;        short* vb0 = vr;
        short* kb1 = kr + 4096;

        // ---- deferred PV of prev phase's tile 1: pure-reg A-operand + live V slot ----
        if (ph > 0) { PV(vprev + 8192, pp0, pp1) }

        // ---- QK^T both tiles, interleaved ----
        floatx16 st0 = {}, st1 = {};
        __builtin_amdgcn_s_setprio(1);
#pragma unroll
        for (int kk = 0; kk < 8; kk++) {
            short8 kf0 = *(short8*)(kb0 + (kk * 2 + h) * 256 + l31 * 8);
            short8 kf1 = *(short8*)(kb1 + (kk * 2 + h) * 256 + l31 * 8);
            st0 = __builtin_amdgcn_mfma_f32_32x32x16_bf16(kf0, qf[kk], st0, 0, 0, 0);
            st1 = __builtin_amdgcn_mfma_f32_32x32x16_bf16(kf1, qf[kk], st1, 0, 0, 0);
        }
        __builtin_amdgcn_s_setprio(0);

        // ---- tile 0: exp -> PV same-phase ----
        short8 pa00, pa01;
        EXP_PACK(st0, pa00, pa01)
        PV(vb0, pa00, pa01)

        // ---- tile 1: exp packs into deferred regs; PV happens next phase ----
        EXP_PACK(st1, pp0, pp1)
        vprev = vr;

        short* t0p = kr; kr = kw; kw = k2; k2 = t0p;
        short* t1p = vr; vr = vw; vw = v2; v2 = t1p;
    }

    // epilogue: deferred PV of phase 63's tile 1
    PV(vprev + 8192, pp0, pp1)

#undef STAGE
#undef EXP_PACK
#undef PV

#pragma unroll
    for (int ct = 0; ct < 8; ct++) {
        int c = cblk * 256 + ct * 32 + l31;
#pragma unroll
        for (int r = 0; r < 16; r++) {
            int q = (r & 3) + 8 * (r >> 2) + 4 * h;
            Op[(long)(mw + q) * CDIM + c] = f2bf(acc[ct][r]);
        }
    }
    if (blockIdx.y == 0) {
        float lsum = (ls0 + ls1) + (ls2 + ls3);
        lsum += __shfl_xor(lsum, 32);
        if (lane < 32) ls[mw + lane] = lsum;
    }
}

// ---------------- combine: attn = (Oa + Ob) / (la + lb), in place over Ob ----------------
__global__ __launch_bounds__(256) void combine_attn(
    const unsigned short* __restrict__ Oa, unsigned short* __restrict__ Ob,
    const float* __restrict__ la, const float* __restrict__ lb)
{
    int i = blockIdx.x * blockDim.x + threadIdx.x;
    int row = i >> 7;
    float inv = 1.0f / (la[row] + lb[row]);
    short8 a = ((const short8*)Oa)[i];
    short8 b = ((const short8*)Ob)[i];
    short8 o;
#pragma unroll
    for (int e = 0; e < 8; e++) o[e] = (short)f2bf((bf2f(a[e]) + bf2f(b[e])) * inv);
    ((short8*)Ob)[i] = o;
}

extern "C" void kernel_launch(void* const* d_in, const int* in_sizes, int n_in,
                              void* d_out, int out_size, void* d_ws, size_t ws_size,
                              hipStream_t stream) {
    const float* x  = (const float*)d_in[0];
    const float* Wq = (const float*)d_in[1];
    const float* bq = (const float*)d_in[2];
    const float* Wk = (const float*)d_in[3];
    const float* bk = (const float*)d_in[4];
    const float* Wv = (const float*)d_in[5];
    const float* bv = (const float*)d_in[6];
    const float* Wo = (const float*)d_in[7];
    const float* bo = (const float*)d_in[8];

    char* ws = (char*)d_ws;
    unsigned short* x_bf   = (unsigned short*)(ws + 0);          // 16 MB (reused as Oa)
    unsigned short* wq_bf  = (unsigned short*)(ws + 16777216);   // 256 KB
    unsigned short* wk_bf  = (unsigned short*)(ws + 17039360);   // 256 KB
    unsigned short* wv_bf  = (unsigned short*)(ws + 17301504);   // 2 MB
    unsigned short* wo_bf  = (unsigned short*)(ws + 19398656);   // 2 MB
    unsigned short* q_bf   = (unsigned short*)(ws + 21495808);   // 2 MB
    unsigned short* k_swz  = (unsigned short*)(ws + 23592960);   // 2 MB (K swizzled)
    unsigned short* v_swz  = (unsigned short*)(ws + 25690112);   // 16 MB (V swizzled)
    unsigned short* attn_bf= (unsigned short*)(ws + 42467328);   // 16 MB (Ob, combined in place)
    float* lsum_a          = (float*)(ws + 59244544);            // 32 KB
    float* lsum_b          = (float*)(ws + 59277312);            // 32 KB

    // all casts in one launch
    cast_all<<<10496, 256, 0, stream>>>(x, Wv, Wo, Wq, Wk,
                                        x_bf, wv_bf, wo_bf, wq_bf, wk_bf);

    // q/k/v projections in one launch (T3/T4 K-loop, 3 blocks/CU)
    gemm_proj<<<dim3(64, 10), 256, 0, stream>>>(x_bf, wq_bf, bq, wk_bf, bk, wv_bf, bv,
                                                q_bf, k_swz, v_swz);

    // fused attention (split-n over gridDim.z); Oa overlays dead x_bf
    attn_pv<<<dim3(32, 4, 2), 512, 0, stream>>>(q_bf, k_swz, v_swz,
                                                x_bf, attn_bf, lsum_a, lsum_b);
    combine_attn<<<4096, 256, 0, stream>>>(x_bf, attn_bf, lsum_a, lsum_b);

    // output projection (T3/T4 K-loop, 3 blocks/CU, f32 out)
    gemm_out<<<dim3(64, 8), 256, 0, stream>>>(attn_bf, wo_bf, bo, (float*)d_out);
}